// Round 24
// baseline (305.943 us; speedup 1.0000x reference)
//
#include <hip/hip_runtime.h>
#include <hip/hip_fp16.h>

#define B 64
#define N 4096
#define M 128

constexpr int T   = 512;    // 8 waves, 1 block/CU (128 KiB LDS)
constexpr int NWG = 256;    // one persistent block per CU; 2 jobs each

__device__ __forceinline__ float2 cadd(float2 a, float2 b){ return make_float2(a.x+b.x, a.y+b.y); }
__device__ __forceinline__ float2 csub(float2 a, float2 b){ return make_float2(a.x-b.x, a.y-b.y); }
__device__ __forceinline__ float2 cmul(float2 a, float2 b){ return make_float2(a.x*b.x - a.y*b.y, a.x*b.y + a.y*b.x); }
__device__ __forceinline__ float2 mulnegi(float2 a){ return make_float2(a.y, -a.x); }
__device__ __forceinline__ float2 muli(float2 a)  { return make_float2(-a.y, a.x); }
__device__ __forceinline__ float2 cis(float ang){ float s, c; __sincosf(ang, &s, &c); return make_float2(c, s); }
__device__ __forceinline__ float2 h2f(__half2 h){ return __half22float2(h); }
__device__ __forceinline__ __half2 f2h(float2 v){ return __floats2half2_rn(v.x, v.y); }

// W64^d = cis(-2*pi*d/64), d = 0..7
__device__ __constant__ const float W64R[8] = {
    1.0f, 0.995184726672197f, 0.980785280403230f, 0.956940335732209f,
    0.923879532511287f, 0.881921264348355f, 0.831469612302545f, 0.773010453362737f };
__device__ __constant__ const float W64I[8] = {
    0.0f, -0.098017140329561f, -0.195090322016128f, -0.290284677254462f,
    -0.382683432365090f, -0.471396736825998f, -0.555570233019602f, -0.634393284163645f };

// forward DFT8 in place (W8 = e^{-i pi/4})
__device__ __forceinline__ void dft8(float2 t[8]) {
    float2 e0=cadd(t[0],t[4]), e1=csub(t[0],t[4]);
    float2 e2=cadd(t[2],t[6]), e3=csub(t[2],t[6]);
    float2 E0=cadd(e0,e2), E2=csub(e0,e2);
    float2 E1=cadd(e1,mulnegi(e3)), E3=cadd(e1,muli(e3));
    float2 o0=cadd(t[1],t[5]), o1=csub(t[1],t[5]);
    float2 o2=cadd(t[3],t[7]), o3=csub(t[3],t[7]);
    float2 O0=cadd(o0,o2), O2=csub(o0,o2);
    float2 O1=cadd(o1,mulnegi(o3)), O3=cadd(o1,muli(o3));
    const float C = 0.70710678118654752f;
    float2 w1O1 = make_float2(C*(O1.x+O1.y), C*(O1.y-O1.x));
    float2 w2O2 = mulnegi(O2);
    float2 w3O3 = make_float2(C*(O3.y-O3.x), -C*(O3.x+O3.y));
    t[0]=cadd(E0,O0);   t[4]=csub(E0,O0);
    t[1]=cadd(E1,w1O1); t[5]=csub(E1,w1O1);
    t[2]=cadd(E2,w2O2); t[6]=csub(E2,w2O2);
    t[3]=cadd(E3,w3O3); t[7]=csub(E3,w3O3);
}

// LDS half2 slot: XOR swizzle n2^(k1&7) => every phase <=2-way (free)
__device__ __forceinline__ int lslot(int k1, int n2, int mc) {
    return (k1 << 9) | ((n2 ^ (k1 & 7)) << 3) | mc;
}

// phase A pass 2: twiddled recombine + global twiddle W4096^{rp*k1} -> LDS
__device__ __forceinline__ void passA2(__half2 pk[8][8], __half2* lz, int rp, int mc) {
    const float2 ws_ = cis(-6.2831853071795864f * (float)rp / 4096.0f);
    const float2 w8  = cis(-6.2831853071795864f * (float)rp / 512.0f);
    float2 pd = make_float2(1.f, 0.f);
    #pragma unroll
    for (int d = 0; d < 8; ++d) {
        const float2 wd = make_float2(W64R[d], W64I[d]);
        float2 t[8];
        t[0] = h2f(pk[0][d]);
        float2 w = wd;
        #pragma unroll
        for (int bb = 1; bb < 8; ++bb) { t[bb] = cmul(h2f(pk[bb][d]), w); w = cmul(w, wd); }
        dft8(t);
        float2 ac = pd;
        #pragma unroll
        for (int c = 0; c < 8; ++c) {
            lz[lslot(8*c+d, rp, mc)] = f2h(cmul(t[c], ac));
            ac = cmul(ac, w8);
        }
        pd = cmul(pd, ws_);
    }
}

// phase B: FFT64 over n2 of own slice k1=rp (in LDS, self-owned, race-free)
__device__ __forceinline__ void phaseB(__half2 pk[8][8], __half2* lz, int rp, int mc) {
    #pragma unroll
    for (int bb = 0; bb < 8; ++bb) {
        float2 t[8];
        #pragma unroll
        for (int a = 0; a < 8; ++a)
            t[a] = h2f(lz[lslot(rp, 8*a+bb, mc)]);
        dft8(t);
        #pragma unroll
        for (int d = 0; d < 8; ++d) pk[bb][d] = f2h(t[d]);
    }
    #pragma unroll
    for (int d = 0; d < 8; ++d) {
        const float2 wd = make_float2(W64R[d], W64I[d]);
        float2 t[8];
        t[0] = h2f(pk[0][d]);
        float2 w = wd;
        #pragma unroll
        for (int bb = 1; bb < 8; ++bb) { t[bb] = cmul(h2f(pk[bb][d]), w); w = cmul(w, wd); }
        dft8(t);
        #pragma unroll
        for (int c = 0; c < 8; ++c)
            lz[lslot(rp, 8*c+d, mc)] = f2h(t[c]);
    }
}

// Hermitian unpack (r17 form, measured best) + coalesced stores
__device__ __forceinline__ void unpackStore(const __half2* lz, float* outRe,
                                            float* outIm, int rp, int mc) {
    #pragma unroll 4
    for (int j = 0; j < 64; ++j) {
        int k   = (j << 6) | rp;
        int kk  = (N - k) & (N - 1);
        int k1p = kk & 63, k2p = kk >> 6;
        float2 Zk = h2f(lz[lslot(rp,  j,   mc)]);
        float2 Zm = h2f(lz[lslot(k1p, k2p, mc)]);
        float2 re = make_float2(0.5f * (Zk.x + Zm.x), 0.5f * (Zk.y + Zm.y));
        float2 im = make_float2(0.5f * (Zk.y - Zm.y), 0.5f * (Zm.x - Zk.x));
        *(float2*)(outRe + (size_t)k * M) = re;
        *(float2*)(outIm + (size_t)k * M) = im;
    }
}

__global__
__attribute__((amdgpu_flat_work_group_size(512, 512), amdgpu_waves_per_eu(2, 2)))
void fft_one(const float* __restrict__ x, float* __restrict__ out) {
    extern __shared__ __half2 lz[];   // [k1][n2 sw][mc] = 128 KiB

    // 256 blocks = 64 batches x 4 qb; bid%8 = b&7 -> co-XCD per batch
    const int bid = blockIdx.x;
    const int b   = ((bid >> 5) << 3) | (bid & 7);
    const int qb  = (bid >> 3) & 3;
    const int tid = threadIdx.x;
    const int mc  = tid & 7;
    const int rp  = tid >> 3;

    const float* xb0 = x + (size_t)b * N * M + qb * 16 + mc * 2;        // job0
    const float* xb1 = xb0 + 64;                                        // job1 (qb+4)
    float* outRe0 = out + (size_t)b * N * M + qb * 16 + mc * 2;
    float* outIm0 = outRe0 + (size_t)B * N * M;

    __half2 pk[8][8];

    // ======== job0 phase A pass 1 ========
    #pragma unroll
    for (int bb = 0; bb < 8; ++bb) {
        float2 t[8];
        #pragma unroll
        for (int a = 0; a < 8; ++a)
            t[a] = *(const float2*)(xb0 + (size_t)(64*(8*a+bb) + rp) * M);
        dft8(t);
        #pragma unroll
        for (int d = 0; d < 8; ++d) pk[bb][d] = f2h(t[d]);
    }
    // ---- prefetch ALL of job1's input into 128 held f32 VGPRs;
    //      streams from HBM under job0's pass2+phaseB+unpack ----
    float2 pf[8][8];
    #pragma unroll
    for (int cc = 0; cc < 8; ++cc)
        #pragma unroll
        for (int a = 0; a < 8; ++a)
            pf[cc][a] = *(const float2*)(xb1 + (size_t)(64*(8*a+cc) + rp) * M);

    passA2(pk, lz, rp, mc);
    __syncthreads();
    phaseB(pk, lz, rp, mc);
    __syncthreads();
    unpackStore(lz, outRe0, outIm0, rp, mc);
    __syncthreads();    // all job0 unpack LDS reads done before job1 overwrites

    // ======== job1 phase A pass 1: entirely from prefetched registers ========
    #pragma unroll
    for (int cc = 0; cc < 8; ++cc) {
        float2 t[8];
        #pragma unroll
        for (int a = 0; a < 8; ++a) t[a] = pf[cc][a];
        dft8(t);
        #pragma unroll
        for (int d = 0; d < 8; ++d) pk[cc][d] = f2h(t[d]);
    }
    passA2(pk, lz, rp, mc);
    __syncthreads();
    phaseB(pk, lz, rp, mc);
    __syncthreads();
    unpackStore(lz, outRe0 + 64, outIm0 + 64, rp, mc);
}

extern "C" void kernel_launch(void* const* d_in, const int* in_sizes, int n_in,
                              void* d_out, int out_size, void* d_ws, size_t ws_size,
                              hipStream_t stream) {
    const float* x = (const float*)d_in[0];
    float* out = (float*)d_out;
    const int lds_bytes = 64 * 64 * 8 * (int)sizeof(__half2);   // 131072
    hipFuncSetAttribute((const void*)fft_one,
                        hipFuncAttributeMaxDynamicSharedMemorySize, lds_bytes);
    fft_one<<<NWG, T, lds_bytes, stream>>>(x, out);
}

// Round 25
// 195.660 us; speedup vs baseline: 1.5636x; 1.5636x over previous
//
#include <hip/hip_runtime.h>
#include <hip/hip_fp16.h>

#define B 64
#define N 4096
#define M 128

constexpr int T   = 512;    // 8 waves; 128 KiB LDS -> 1 block/CU; VGPR cap 128
constexpr int NWG = 512;    // 64 batches x 8 channel-groups (16 ch each)

__device__ __forceinline__ float2 cadd(float2 a, float2 b){ return make_float2(a.x+b.x, a.y+b.y); }
__device__ __forceinline__ float2 csub(float2 a, float2 b){ return make_float2(a.x-b.x, a.y-b.y); }
__device__ __forceinline__ float2 cmul(float2 a, float2 b){ return make_float2(a.x*b.x - a.y*b.y, a.x*b.y + a.y*b.x); }
__device__ __forceinline__ float2 mulnegi(float2 a){ return make_float2(a.y, -a.x); }
__device__ __forceinline__ float2 muli(float2 a)  { return make_float2(-a.y, a.x); }
__device__ __forceinline__ float2 cis(float ang){ float s, c; __sincosf(ang, &s, &c); return make_float2(c, s); }
__device__ __forceinline__ float2 h2f(__half2 h){ return __half22float2(h); }
__device__ __forceinline__ __half2 f2h(float2 v){ return __floats2half2_rn(v.x, v.y); }
__device__ __forceinline__ __half2 u2h(unsigned u){ return *(__half2*)&u; }

// W64^d = cis(-2*pi*d/64), d = 0..7
__device__ __constant__ const float W64R[8] = {
    1.0f, 0.995184726672197f, 0.980785280403230f, 0.956940335732209f,
    0.923879532511287f, 0.881921264348355f, 0.831469612302545f, 0.773010453362737f };
__device__ __constant__ const float W64I[8] = {
    0.0f, -0.098017140329561f, -0.195090322016128f, -0.290284677254462f,
    -0.382683432365090f, -0.471396736825998f, -0.555570233019602f, -0.634393284163645f };

// forward DFT8 in place (W8 = e^{-i pi/4})
__device__ __forceinline__ void dft8(float2 t[8]) {
    float2 e0=cadd(t[0],t[4]), e1=csub(t[0],t[4]);
    float2 e2=cadd(t[2],t[6]), e3=csub(t[2],t[6]);
    float2 E0=cadd(e0,e2), E2=csub(e0,e2);
    float2 E1=cadd(e1,mulnegi(e3)), E3=cadd(e1,muli(e3));
    float2 o0=cadd(t[1],t[5]), o1=csub(t[1],t[5]);
    float2 o2=cadd(t[3],t[7]), o3=csub(t[3],t[7]);
    float2 O0=cadd(o0,o2), O2=csub(o0,o2);
    float2 O1=cadd(o1,mulnegi(o3)), O3=cadd(o1,muli(o3));
    const float C = 0.70710678118654752f;
    float2 w1O1 = make_float2(C*(O1.x+O1.y), C*(O1.y-O1.x));
    float2 w2O2 = mulnegi(O2);
    float2 w3O3 = make_float2(C*(O3.y-O3.x), -C*(O3.x+O3.y));
    t[0]=cadd(E0,O0);   t[4]=csub(E0,O0);
    t[1]=cadd(E1,w1O1); t[5]=csub(E1,w1O1);
    t[2]=cadd(E2,w2O2); t[6]=csub(E2,w2O2);
    t[3]=cadd(E3,w3O3); t[7]=csub(E3,w3O3);
}

// LDS half2 slot: XOR swizzle n2^(k1&7) => stage phases <=2-way (free)
__device__ __forceinline__ int lslot(int k1, int n2, int mc) {
    return (k1 << 9) | ((n2 ^ (k1 & 7)) << 3) | mc;
}

__global__ __launch_bounds__(T, 2)
void fft_one(const float* __restrict__ x, float* __restrict__ out) {
    extern __shared__ __half2 lz[];   // [k1][n2 sw][mc] = 64*64*8 half2 = 128 KiB

    // bid%8 = b&7 -> all 8 channel-groups of a batch on one XCD
    const int bid = blockIdx.x;
    const int b   = ((bid >> 6) << 3) | (bid & 7);
    const int mcg = (bid >> 3) & 7;
    const int tid = threadIdx.x;
    const int mc  = tid & 7;        // packed channel pair within group
    const int rp  = tid >> 3;       // phase A: n2 ; phase B: k1

    const float* xb = x + (size_t)b * N * M + mcg * 16 + mc * 2;

    __half2 pk[8][8];   // fp16-packed pass-1 intermediates (64 VGPRs, static idx)

    // ======== phase A: FFT64 over n1 of column n2=rp ========
    #pragma unroll
    for (int bb = 0; bb < 8; ++bb) {
        float2 t[8];
        #pragma unroll
        for (int a = 0; a < 8; ++a)
            t[a] = *(const float2*)(xb + (size_t)(64*(8*a+bb) + rp) * M);
        dft8(t);
        #pragma unroll
        for (int d = 0; d < 8; ++d) pk[bb][d] = f2h(t[d]);
    }
    {
        const float2 ws_ = cis(-6.2831853071795864f * (float)rp / 4096.0f);
        const float2 w8  = cis(-6.2831853071795864f * (float)rp / 512.0f);
        float2 pd = make_float2(1.f, 0.f);
        #pragma unroll
        for (int d = 0; d < 8; ++d) {
            const float2 wd = make_float2(W64R[d], W64I[d]);
            float2 t[8];
            t[0] = h2f(pk[0][d]);
            float2 w = wd;
            #pragma unroll
            for (int bb = 1; bb < 8; ++bb) { t[bb] = cmul(h2f(pk[bb][d]), w); w = cmul(w, wd); }
            dft8(t);
            float2 ac = pd;
            #pragma unroll
            for (int c = 0; c < 8; ++c) {
                lz[lslot(8*c+d, rp, mc)] = f2h(cmul(t[c], ac));
                ac = cmul(ac, w8);
            }
            pd = cmul(pd, ws_);
        }
    }
    __syncthreads();

    // ======== phase B: FFT64 over n2 of own slice k1=rp ========
    #pragma unroll
    for (int bb = 0; bb < 8; ++bb) {
        float2 t[8];
        #pragma unroll
        for (int a = 0; a < 8; ++a)
            t[a] = h2f(lz[lslot(rp, 8*a+bb, mc)]);
        dft8(t);
        #pragma unroll
        for (int d = 0; d < 8; ++d) pk[bb][d] = f2h(t[d]);
    }
    #pragma unroll
    for (int d = 0; d < 8; ++d) {
        const float2 wd = make_float2(W64R[d], W64I[d]);
        float2 t[8];
        t[0] = h2f(pk[0][d]);
        float2 w = wd;
        #pragma unroll
        for (int bb = 1; bb < 8; ++bb) { t[bb] = cmul(h2f(pk[bb][d]), w); w = cmul(w, wd); }
        dft8(t);
        #pragma unroll
        for (int c = 0; c < 8; ++c)
            lz[lslot(rp, 8*c+d, mc)] = f2h(t[c]);   // Z[k2=8c+d], self-owned slice
    }
    __syncthreads();

    // ======== Hermitian unpack, float4-wide (channel-quad per thread) ========
    // task (k, q): planes 2q,2q+1 adjacent in LDS -> one b64 read per spectrum
    // point; one float4 re + one float4 im store (16 B/lane, 4 lanes = 64 B/row).
    float* outRe = out + (size_t)b * N * M + mcg * 16;
    float* outIm = outRe + (size_t)B * N * M;
    const int q   = tid & 3;
    const int kb0 = tid >> 2;          // 0..127
    #pragma unroll 4
    for (int it = 0; it < 32; ++it) {
        int k  = kb0 + (it << 7);
        int kk = (N - k) & (N - 1);
        int ka = k & 63,  kb = k >> 6;
        int ma = kk & 63, mb = kk >> 6;
        uint2 A  = *(const uint2*)&lz[lslot(ka, kb, 2 * q)];
        uint2 Bv = *(const uint2*)&lz[lslot(ma, mb, 2 * q)];
        float2 Zk0 = h2f(u2h(A.x)),  Zk1 = h2f(u2h(A.y));
        float2 Zm0 = h2f(u2h(Bv.x)), Zm1 = h2f(u2h(Bv.y));
        float4 re, im;
        re.x = 0.5f * (Zk0.x + Zm0.x); im.x = 0.5f * (Zk0.y - Zm0.y);
        re.y = 0.5f * (Zk0.y + Zm0.y); im.y = 0.5f * (Zm0.x - Zk0.x);
        re.z = 0.5f * (Zk1.x + Zm1.x); im.z = 0.5f * (Zk1.y - Zm1.y);
        re.w = 0.5f * (Zk1.y + Zm1.y); im.w = 0.5f * (Zm1.x - Zk1.x);
        *(float4*)(outRe + (size_t)k * M + 4 * q) = re;
        *(float4*)(outIm + (size_t)k * M + 4 * q) = im;
    }
}

extern "C" void kernel_launch(void* const* d_in, const int* in_sizes, int n_in,
                              void* d_out, int out_size, void* d_ws, size_t ws_size,
                              hipStream_t stream) {
    const float* x = (const float*)d_in[0];
    float* out = (float*)d_out;
    const int lds_bytes = 64 * 64 * 8 * (int)sizeof(__half2);   // 131072
    hipFuncSetAttribute((const void*)fft_one,
                        hipFuncAttributeMaxDynamicSharedMemorySize, lds_bytes);
    fft_one<<<NWG, T, lds_bytes, stream>>>(x, out);
}